// Round 8
// baseline (150.025 us; speedup 1.0000x reference)
//
#include <hip/hip_runtime.h>

// MPS tensor-train classifier, B=16384, D=784, BOND=5, OUT=10.
//
// res[b] = carry0(x0) . (prod_{m=0..781} M_m(x[m+1])) . vlast(x783)
// Pair p (sites 2p+1, 2p+2):  C_p = P0 + xa*P1 + xb*P2 + xa*xb*P3
// (P0..P3 prepacked, 25 floats each, 100 floats/pair; N = A1-A0).
// Pairs >= BWD_P0 stored TRANSPOSED for the bwd row-vector chain.
//
// Round-8 vs round-7: 512-THREAD BLOCKS (8 waves). Round 7's SGPR_Count=112
// capped the 800-SGPR/SIMD file at 7 waves/SIMD = 28 waves/CU, and 16-wave
// blocks made that all-or-nothing -> 1 block/CU (Occupancy 37.7%). With
// 8-wave blocks, 3 blocks/CU = 24 waves/CU fit BOTH caps (SGPR: 6x112<=800
// per SIMD; LDS: 3x44.8 KB <= 160 KB). Same no-spill math, finer quantum.
//   front block: wave 0 = fwd vec (site0 + pairs 0..40),
//                waves 1..7 = 22-pair matrix segments (41..194)
//   back block:  waves 0..6 = 22-pair matrix segments (195..348),
//                wave 7 = bwd vec (site781 + pairs 389..349 desc, transposed)
// Single-phase combine: 7 matbuf slots, ONE barrier (round 7 had three).
// f/g exchanged via d_out; finalize computes res*fc_w + fc_b.

constexpr int Bn     = 16384;
constexpr int Dn     = 784;
constexpr int NOUT   = 10;
constexpr int NPAIR  = 390;   // pairs cover sites 1..780
constexpr int PKP    = 100;   // floats per pair block (400 B): mat q at q*25
constexpr int BWD_P0 = 349;   // bwd vec pairs 349..389 (stored transposed)
constexpr int VECP   = 41;    // pairs per vec wave
constexpr int MATP   = 22;    // pairs per matrix wave (7 per half)

// ---- prepack: pair blocks, plain 25-float row-major mats ----
// cores_mid element (m,l,i,k) at (m*5+l)*10 + i*5 + k
__global__ void prepack_pairs(const float* __restrict__ cm, float* __restrict__ pk)
{
    int idx = blockIdx.x * 256 + threadIdx.x;
    if (idx >= NPAIR * 100) return;
    int p = idx / 100, rest = idx - p * 100;
    int q = rest / 25, e = rest - q * 25;
    int l = e / 5, r = e - l * 5;
    int m1 = 2 * p + 1, m2 = 2 * p + 2;
    const float* L = cm + (size_t)(m1 * 5 + l) * 10;
    float acc = 0.f;
#pragma unroll
    for (int k = 0; k < 5; ++k) {
        float Lk = (q & 1) ? (L[5 + k] - L[k]) : L[k];
        const float* R = cm + (size_t)(m2 * 5 + k) * 10;
        float Rk = (q & 2) ? (R[5 + r] - R[r]) : R[r];
        acc = fmaf(Lk, Rk, acc);
    }
    int wl = l, wr = r;
    if (p >= BWD_P0) { wl = r; wr = l; }   // store C^T for the bwd wave
    pk[(size_t)p * PKP + q * 25 + wl * 5 + wr] = acc;
}

// C = P0 + xa*P1 + xb*P2 + xa*xb*P3.  Per element: v_mul(s) + 2x v_fma(s)
// + v_add(s) — exactly one SGPR source per instruction, no v_mov staging.
__device__ __forceinline__ void buildC(const float* __restrict__ s,
                                       float xa, float xb, float C[25]) {
    const float xab = xa * xb;
#pragma unroll
    for (int k = 0; k < 25; ++k) {
        float t = xab * s[75 + k];
        t = fmaf(xb, s[50 + k], t);
        t = fmaf(xa, s[25 + k], t);
        C[k] = t + s[k];
    }
}

// c <- c @ C   (row 5-vector)
__device__ __forceinline__ void vstep(float c[5], const float C[25]) {
    float t[5];
#pragma unroll
    for (int r = 0; r < 5; ++r) t[r] = c[0] * C[r];
#pragma unroll
    for (int l = 1; l < 5; ++l)
#pragma unroll
        for (int r = 0; r < 5; ++r) t[r] = fmaf(c[l], C[l * 5 + r], t[r]);
#pragma unroll
    for (int r = 0; r < 5; ++r) c[r] = t[r];
}

// M <- M @ C   (in-place, row by row)
__device__ __forceinline__ void mstep(float M[25], const float C[25]) {
#pragma unroll
    for (int i = 0; i < 5; ++i) {
        float t[5];
#pragma unroll
        for (int r = 0; r < 5; ++r) t[r] = M[i * 5] * C[r];
#pragma unroll
        for (int l = 1; l < 5; ++l)
#pragma unroll
            for (int r = 0; r < 5; ++r) t[r] = fmaf(M[i * 5 + l], C[l * 5 + r], t[r]);
#pragma unroll
        for (int r = 0; r < 5; ++r) M[i * 5 + r] = t[r];
    }
}

__global__ __launch_bounds__(512, 4)
void mps_half_kernel(const float* __restrict__ x,          // [B, D]
                     const float* __restrict__ core_first, // [2,5]
                     const float* __restrict__ cores_mid,  // [782,5,2,5]
                     const float* __restrict__ core_last,  // [5,2]
                     const float* __restrict__ pk,         // [390][100]
                     float* __restrict__ out)              // [B,10]: f|g
{
    __shared__ float matbuf[7][25][64];   // 44.8 KB -> 3 blocks/CU fit 160 KB

    const int lane = threadIdx.x & 63;
    const int wseg = __builtin_amdgcn_readfirstlane(threadIdx.x >> 6);  // 0..7
    const int half = blockIdx.x & 1;           // 0 = front, 1 = back
    const int row  = (blockIdx.x >> 1) * 64 + lane;
    const float*  __restrict__ xr  = x + (size_t)row * Dn;
    const float2* __restrict__ xr2 = (const float2*)xr;   // 392 entries

    const bool isVec = (half == 0) ? (wseg == 0) : (wseg == 7);

    float M[25];   // matrix waves: running product
    float cl[5];   // vec waves: running vector
    float C[25];

    if (!isVec) {
        const int p0 = (half == 0) ? (VECP + MATP * (wseg - 1))
                                   : (195 + MATP * wseg);
        const float* __restrict__ s = pk + (size_t)p0 * PKP;
#pragma unroll
        for (int k = 0; k < 25; ++k) M[k] = (k % 6 == 0) ? 1.0f : 0.0f;
#pragma unroll 1
        for (int i = 0; i < MATP; ++i) {
            const float2 xv = xr2[p0 + i + 1];   // {x[2p+2], x[2p+3]}
            buildC(s, xv.x, xv.y, C);
            mstep(M, C);
            s += PKP;
        }
        // write slot: front waves 1..7 -> 0..6; back waves 0..6 -> 0..6
        const int slot = (half == 0) ? (wseg - 1) : wseg;
#pragma unroll
        for (int k = 0; k < 25; ++k) matbuf[slot][k][lane] = M[k];
    } else if (half == 0) {
        // ---- fwd vec: carry0, site 0 (single), pairs 0..40 ----
        const float2 x01 = xr2[0];
        float cn[5];
#pragma unroll
        for (int r = 0; r < 5; ++r)
            cl[r] = fmaf(x01.x, core_first[5 + r] - core_first[r], core_first[r]);
        const float* cm0 = cores_mid;            // site m=0
#pragma unroll
        for (int r = 0; r < 5; ++r) {
            float a = 0.f;
#pragma unroll
            for (int l = 0; l < 5; ++l) {
                float mm = fmaf(x01.y, cm0[l * 10 + 5 + r] - cm0[l * 10 + r],
                                cm0[l * 10 + r]);
                a = fmaf(cl[l], mm, a);
            }
            cn[r] = a;
        }
#pragma unroll
        for (int r = 0; r < 5; ++r) cl[r] = cn[r];
        const float* __restrict__ s = pk;
#pragma unroll 1
        for (int p = 0; p < VECP; ++p) {
            const float2 xv = xr2[p + 1];
            buildC(s, xv.x, xv.y, C);
            vstep(cl, C);
            s += PKP;
        }
    } else {
        // ---- bwd vec: vlast, site 781 (single), pairs 389..349 desc ----
        const float2 xz = xr2[391];              // {x[782], x[783]}
        float vl[5], vn[5];
#pragma unroll
        for (int l = 0; l < 5; ++l)
            vl[l] = fmaf(xz.y, core_last[2 * l + 1] - core_last[2 * l],
                         core_last[2 * l]);
        const float* cmL = cores_mid + (size_t)781 * 50;   // site m=781
#pragma unroll
        for (int l = 0; l < 5; ++l) {
            float a = 0.f;
#pragma unroll
            for (int r = 0; r < 5; ++r) {
                float mm = fmaf(xz.x, cmL[l * 10 + 5 + r] - cmL[l * 10 + r],
                                cmL[l * 10 + r]);
                a = fmaf(mm, vl[r], a);
            }
            vn[l] = a;
        }
#pragma unroll
        for (int l = 0; l < 5; ++l) cl[l] = vn[l];
        const float* __restrict__ s = pk + (size_t)(NPAIR - 1) * PKP;
#pragma unroll 1
        for (int p = NPAIR - 1; p >= BWD_P0; --p) {
            const float2 xv = xr2[p + 1];
            buildC(s, xv.x, xv.y, C);            // transposed pk
            vstep(cl, C);                        // row-form of column chain
            s -= PKP;
        }
    }

    __syncthreads();   // single barrier: all 7 matrices ready

    if (isVec) {
        float* orow = out + (size_t)row * NOUT;
        if (half == 0) {
            // f = cl @ S0 @ ... @ S6 (ascending slots, row form)
#pragma unroll 1
            for (int s2 = 0; s2 < 7; ++s2) {
                float t[5];
#pragma unroll
                for (int r = 0; r < 5; ++r) t[r] = cl[0] * matbuf[s2][r][lane];
#pragma unroll
                for (int l = 1; l < 5; ++l)
#pragma unroll
                    for (int r = 0; r < 5; ++r)
                        t[r] = fmaf(cl[l], matbuf[s2][l * 5 + r][lane], t[r]);
#pragma unroll
                for (int r = 0; r < 5; ++r) cl[r] = t[r];
            }
#pragma unroll
            for (int i = 0; i < 5; ++i) orow[i] = cl[i];        // f
        } else {
            // g^T = g_col^T @ S6^T @ ... @ S0^T (descending slots, column form)
#pragma unroll 1
            for (int s2 = 6; s2 >= 0; --s2) {
                float t[5];
#pragma unroll
                for (int l = 0; l < 5; ++l) {
                    float a = matbuf[s2][l * 5][lane] * cl[0];
#pragma unroll
                    for (int r = 1; r < 5; ++r)
                        a = fmaf(matbuf[s2][l * 5 + r][lane], cl[r], a);
                    t[l] = a;
                }
#pragma unroll
                for (int l = 0; l < 5; ++l) cl[l] = t[l];
            }
#pragma unroll
            for (int i = 0; i < 5; ++i) orow[5 + i] = cl[i];    // g
        }
    }
}

// out[row] currently holds [f0..f4, g0..g4]; replace with res*fc_w + fc_b
__global__ __launch_bounds__(256)
void finalize_kernel(const float* __restrict__ fc_w, const float* __restrict__ fc_b,
                     float* __restrict__ out)
{
    const int row = blockIdx.x * 256 + threadIdx.x;   // 16384 threads
    float* o = out + (size_t)row * NOUT;
    float f[5], g[5];
#pragma unroll
    for (int i = 0; i < 5; ++i) { f[i] = o[i]; g[i] = o[5 + i]; }
    float res = f[0] * g[0];
#pragma unroll
    for (int i = 1; i < 5; ++i) res = fmaf(f[i], g[i], res);
#pragma unroll
    for (int k = 0; k < NOUT; ++k) o[k] = fmaf(res, fc_w[k], fc_b[k]);
}

extern "C" void kernel_launch(void* const* d_in, const int* in_sizes, int n_in,
                              void* d_out, int out_size, void* d_ws, size_t ws_size,
                              hipStream_t stream) {
    const float* x          = (const float*)d_in[0];
    const float* core_first = (const float*)d_in[1];
    const float* cores_mid  = (const float*)d_in[2];
    const float* core_last  = (const float*)d_in[3];
    const float* fc_w       = (const float*)d_in[4];
    const float* fc_b       = (const float*)d_in[5];
    float* out              = (float*)d_out;
    float* pk               = (float*)d_ws;   // 390*100*4 = 156,000 B

    hipLaunchKernelGGL(prepack_pairs, dim3((NPAIR * 100 + 255) / 256), dim3(256),
                       0, stream, cores_mid, pk);
    hipLaunchKernelGGL(mps_half_kernel, dim3(Bn / 64 * 2), dim3(512), 0, stream,
                       x, core_first, cores_mid, core_last, pk, out);
    hipLaunchKernelGGL(finalize_kernel, dim3(Bn / 256), dim3(256), 0, stream,
                       fc_w, fc_b, out);
}